// Round 1
// baseline (498.954 us; speedup 1.0000x reference)
//
#include <hip/hip_runtime.h>

// ---------------------------------------------------------------------------
// HyperMoMixLinear on MI355X.
// Pipeline (all bf16 MFMA GEMMs, fp32 accumulate):
//  K1 compress:  c = silu(x@Wc+bc)            [512,1024]@[1024,256]
//  K2 hyper:     H = silu(c@[W1a|W2a|Wm1]+b), biasout = c@Wb+bb   (N=3328)
//  K3 prep:      coeffs=softmax(mixh@Wm2+bm2), ratio=c@Wr+br, G=coeff*h (+tails)
//  K4 biggemm:   M1 = G1@W1b(+coeff-mixed b1b)  [512,1024]@[1024,32768]
//  K6 monarch1:  x1o = einsum(x, M1) -> XT (transposed layout)
//  K5 biggemm:   M2 = G2@W2b(+b2b)   (reuses M buffer)
//  K7 monarch2:  out = einsum(XT, M2)*ratio + biasout
// A-operands live in workspace in MFMA "unit" layout: 16B unit = 8 consecutive
// k-channels of one row; unit index = (k>>3)*512 + token. This makes GEMM
// A-staging a pure global_load_lds and all fragment ds_read_b128 dense.
// ---------------------------------------------------------------------------

typedef __bf16 bf16x8 __attribute__((ext_vector_type(8)));
typedef float  fx4    __attribute__((ext_vector_type(4)));

#define NN 32768

__device__ __forceinline__ unsigned short f2bf(float f) {
  union { float f; unsigned u; } v; v.f = f;
  unsigned r = v.u + 0x7FFFu + ((v.u >> 16) & 1u);
  return (unsigned short)(r >> 16);
}
__device__ __forceinline__ unsigned pk2(float lo, float hi) {
  return (unsigned)f2bf(lo) | ((unsigned)f2bf(hi) << 16);
}
__device__ __forceinline__ uint4 pk8(const float* v) {
  uint4 u; u.x = pk2(v[0], v[1]); u.y = pk2(v[2], v[3]);
  u.z = pk2(v[4], v[5]); u.w = pk2(v[6], v[7]); return u;
}
__device__ __forceinline__ float b2f(unsigned short s) {
  union { unsigned u; float f; } v; v.u = ((unsigned)s) << 16; return v.f;
}
__device__ __forceinline__ float silu_f(float x) { return x / (1.f + __expf(-x)); }

__device__ __forceinline__ void gl2lds16(const void* g, void* l) {
  __builtin_amdgcn_global_load_lds(
      (const __attribute__((address_space(1))) unsigned int*)g,
      (__attribute__((address_space(3))) unsigned int*)l, 16, 0, 0);
}

#define MFMA(a, b, c) __builtin_amdgcn_mfma_f32_16x16x32_bf16((a), (b), (c), 0, 0, 0)

// ---------------------------------------------------------------------------
// K1: c = silu(x @ Wc + bc).  M=512,K=1024,N=256.  BM=BN=64, BK=64.
// Writes c into unit layout (36 runs: 32 data + 1 const-one + 3 zero).
// ---------------------------------------------------------------------------
__global__ __launch_bounds__(256) void k1_compress(
    const float* __restrict__ x, const float* __restrict__ Wc,
    const float* __restrict__ bc, uint4* __restrict__ c_u4) {
  const int tid = threadIdx.x;
  const int m0 = blockIdx.x * 64, n0 = blockIdx.y * 64;
  __shared__ uint4 As[8 * 64];
  __shared__ uint4 Bs[8 * 64];
  const bf16x8* Af = reinterpret_cast<const bf16x8*>(As);
  const bf16x8* Bf = reinterpret_cast<const bf16x8*>(Bs);
  const int lane = tid & 63, w = tid >> 6;
  const int q = lane >> 4, rr = lane & 15;
  const int wm = (w >> 1) * 32, wn = (w & 1) * 32;
  fx4 a00 = 0, a01 = 0, a10 = 0, a11 = 0;

  for (int kt = 0; kt < 16; ++kt) {
    const int k0 = kt * 64;
    {  // A: x fp32 -> bf16 units [run][m]
      const int run = tid & 7, mb = tid >> 3;
#pragma unroll
      for (int s = 0; s < 2; ++s) {
        const int m = mb + 32 * s;
        const float* src = x + (size_t)(m0 + m) * 1024 + k0 + run * 8;
        float4 f0 = *(const float4*)src;
        float4 f1 = *(const float4*)(src + 4);
        uint4 u; u.x = pk2(f0.x, f0.y); u.y = pk2(f0.z, f0.w);
        u.z = pk2(f1.x, f1.y); u.w = pk2(f1.z, f1.w);
        As[run * 64 + m] = u;
      }
    }
    {  // B: Wc k-major -> transposed units; scalar coalesced loads
      const int col = tid & 63, qr = tid >> 6;
      float v[16];
      const float* wp = Wc + (size_t)(k0 + qr * 16) * 256 + n0 + col;
#pragma unroll
      for (int kk = 0; kk < 16; ++kk) v[kk] = wp[(size_t)kk * 256];
      Bs[(qr * 2 + 0) * 64 + col] = pk8(v);
      Bs[(qr * 2 + 1) * 64 + col] = pk8(v + 8);
    }
    __syncthreads();
#pragma unroll
    for (int ks = 0; ks < 2; ++ks) {
      const int ro = (ks * 4 + q) * 64;
      bf16x8 fa0 = Af[ro + wm + rr];
      bf16x8 fa1 = Af[ro + wm + 16 + rr];
      bf16x8 fb0 = Bf[ro + wn + rr];
      bf16x8 fb1 = Bf[ro + wn + 16 + rr];
      a00 = MFMA(fa0, fb0, a00); a01 = MFMA(fa0, fb1, a01);
      a10 = MFMA(fa1, fb0, a10); a11 = MFMA(fa1, fb1, a11);
    }
    __syncthreads();
  }
  {  // tail: A const-one channel, B row = bc
    const int r4 = tid >> 6, m = tid & 63;
    uint4 u; u.x = (r4 == 0) ? 0x3F80u : 0u; u.y = 0; u.z = 0; u.w = 0;
    As[r4 * 64 + m] = u;
    uint4 ub; ub.x = (r4 == 0) ? (unsigned)f2bf(bc[n0 + m]) : 0u;
    ub.y = 0; ub.z = 0; ub.w = 0;
    Bs[r4 * 64 + m] = ub;
  }
  __syncthreads();
  {
    const int ro = q * 64;
    bf16x8 fa0 = Af[ro + wm + rr];
    bf16x8 fa1 = Af[ro + wm + 16 + rr];
    bf16x8 fb0 = Bf[ro + wn + rr];
    bf16x8 fb1 = Bf[ro + wn + 16 + rr];
    a00 = MFMA(fa0, fb0, a00); a01 = MFMA(fa0, fb1, a01);
    a10 = MFMA(fa1, fb0, a10); a11 = MFMA(fa1, fb1, a11);
  }
  // epilogue: silu -> c units (scattered u16 stores, small)
  unsigned short* c16 = (unsigned short*)c_u4;
#pragma unroll
  for (int fi = 0; fi < 2; ++fi) {
#pragma unroll
    for (int fj = 0; fj < 2; ++fj) {
      fx4 v = (fi == 0) ? (fj == 0 ? a00 : a01) : (fj == 0 ? a10 : a11);
      const int cc = n0 + wn + fj * 16 + rr;
#pragma unroll
      for (int reg = 0; reg < 4; ++reg) {
        const int t = m0 + wm + fi * 16 + q * 4 + reg;
        c16[((size_t)(cc >> 3) * 512 + t) * 8 + (cc & 7)] = f2bf(silu_f(v[reg]));
      }
    }
  }
  if (blockIdx.y == 0) {  // const-one run 32 + zero runs 33..35
    const int r4 = tid >> 6, m = tid & 63;
    uint4 u; u.x = (r4 == 0) ? 0x3F80u : 0u; u.y = 0; u.z = 0; u.w = 0;
    c_u4[(size_t)(32 + r4) * 512 + m0 + m] = u;
  }
}

// ---------------------------------------------------------------------------
// K2: H = silu(c@{W1a,W2a,Wm1}+bias), biasout = c@Wb+bb.
// M=512, K=256(+tail), N=3328. BM=BN=64. Column category uniform per tile.
// ---------------------------------------------------------------------------
__global__ __launch_bounds__(256) void k2_hyper(
    const uint4* __restrict__ c_u4,
    const float* __restrict__ W1a, const float* __restrict__ b1a,
    const float* __restrict__ W2a, const float* __restrict__ b2a,
    const float* __restrict__ Wm1, const float* __restrict__ bm1,
    const float* __restrict__ Wb, const float* __restrict__ bb,
    unsigned short* __restrict__ H, float* __restrict__ biasout) {
  const int tid = threadIdx.x;
  const int m0 = blockIdx.x * 64, n0 = blockIdx.y * 64;
  __shared__ uint4 As[8 * 64];
  __shared__ uint4 Bs[8 * 64];
  const bf16x8* Af = reinterpret_cast<const bf16x8*>(As);
  const bf16x8* Bf = reinterpret_cast<const bf16x8*>(Bs);
  const int lane = tid & 63, w = tid >> 6;
  const int q = lane >> 4, rr = lane & 15;
  const int wm = (w >> 1) * 32, wn = (w & 1) * 32;

  const float* bbase; const float* biasv; int bstride;
  if (n0 < 1024) {
    const int kx = n0 >> 8;
    bbase = W1a + (size_t)kx * 65536 + (n0 & 255); bstride = 256;
    biasv = b1a + kx * 256 + (n0 & 255);
  } else if (n0 < 2048) {
    const int mm = n0 - 1024; const int kx = mm >> 8;
    bbase = W2a + (size_t)kx * 65536 + (mm & 255); bstride = 256;
    biasv = b2a + kx * 256 + (mm & 255);
  } else if (n0 < 2304) {
    bbase = Wm1 + (n0 - 2048); bstride = 256; biasv = bm1 + (n0 - 2048);
  } else {
    bbase = Wb + (n0 - 2304); bstride = 1024; biasv = bb + (n0 - 2304);
  }

  fx4 a00 = 0, a01 = 0, a10 = 0, a11 = 0;
  for (int kt = 0; kt < 4; ++kt) {
#pragma unroll
    for (int s = 0; s < 2; ++s) {
      const int run = w * 2 + s;
      gl2lds16(c_u4 + (size_t)(kt * 8 + run) * 512 + m0 + lane, (void*)(As + run * 64));
    }
    {
      const int col = tid & 63, qr = tid >> 6;
      float v[16];
      const float* wp = bbase + (size_t)(kt * 64 + qr * 16) * bstride + col;
#pragma unroll
      for (int kk = 0; kk < 16; ++kk) v[kk] = wp[(size_t)kk * bstride];
      Bs[(qr * 2 + 0) * 64 + col] = pk8(v);
      Bs[(qr * 2 + 1) * 64 + col] = pk8(v + 8);
    }
    __syncthreads();
#pragma unroll
    for (int ks = 0; ks < 2; ++ks) {
      const int ro = (ks * 4 + q) * 64;
      bf16x8 fa0 = Af[ro + wm + rr];
      bf16x8 fa1 = Af[ro + wm + 16 + rr];
      bf16x8 fb0 = Bf[ro + wn + rr];
      bf16x8 fb1 = Bf[ro + wn + 16 + rr];
      a00 = MFMA(fa0, fb0, a00); a01 = MFMA(fa0, fb1, a01);
      a10 = MFMA(fa1, fb0, a10); a11 = MFMA(fa1, fb1, a11);
    }
    __syncthreads();
  }
  {  // tail
    gl2lds16(c_u4 + (size_t)(32 + w) * 512 + m0 + lane, (void*)(As + w * 64));
    const int r4 = tid >> 6, col = tid & 63;
    uint4 ub; ub.x = (r4 == 0) ? (unsigned)f2bf(biasv[col]) : 0u;
    ub.y = 0; ub.z = 0; ub.w = 0;
    Bs[r4 * 64 + col] = ub;
  }
  __syncthreads();
  {
    const int ro = q * 64;
    bf16x8 fa0 = Af[ro + wm + rr];
    bf16x8 fa1 = Af[ro + wm + 16 + rr];
    bf16x8 fb0 = Bf[ro + wn + rr];
    bf16x8 fb1 = Bf[ro + wn + 16 + rr];
    a00 = MFMA(fa0, fb0, a00); a01 = MFMA(fa0, fb1, a01);
    a10 = MFMA(fa1, fb0, a10); a11 = MFMA(fa1, fb1, a11);
  }
#pragma unroll
  for (int fi = 0; fi < 2; ++fi) {
#pragma unroll
    for (int fj = 0; fj < 2; ++fj) {
      fx4 v = (fi == 0) ? (fj == 0 ? a00 : a01) : (fj == 0 ? a10 : a11);
      const int cc = n0 + wn + fj * 16 + rr;
#pragma unroll
      for (int reg = 0; reg < 4; ++reg) {
        const int t = m0 + wm + fi * 16 + q * 4 + reg;
        if (n0 < 2304) H[(size_t)t * 2304 + cc] = f2bf(silu_f(v[reg]));
        else           biasout[(size_t)t * 1024 + (cc - 2304)] = v[reg];
      }
    }
  }
}

// ---------------------------------------------------------------------------
// K3: coeffs = softmax(mixh@Wm2+bm2); ratio = c@Wr+br;
//     G1/G2 units = coeff * h (bf16, unit layout) + coeff run 128 + zero runs.
// grid 8 blocks x 64 tokens.
// ---------------------------------------------------------------------------
__global__ __launch_bounds__(256) void k3_prep(
    const unsigned short* __restrict__ H, const unsigned short* __restrict__ c16,
    const float* __restrict__ Wm2, const float* __restrict__ bm2,
    const float* __restrict__ Wr, const float* __restrict__ br,
    uint4* __restrict__ G1u, uint4* __restrict__ G2u, float* __restrict__ ratio) {
  const int tid = threadIdx.x;
  const int t0 = blockIdx.x * 64;
  __shared__ float lg[64][4];
  __shared__ float cf[64][4];
  __shared__ float rp[4][64];
  {
    const int tl = tid >> 2, kx = tid & 3;
    const unsigned short* hrow = H + (size_t)(t0 + tl) * 2304 + 2048;
    float s = 0.f;
    for (int cc = 0; cc < 256; ++cc) s += b2f(hrow[cc]) * Wm2[cc * 4 + kx];
    lg[tl][kx] = s + bm2[kx];
  }
  __syncthreads();
  {
    const int tl = tid >> 2, kx = tid & 3;
    float l0 = lg[tl][0], l1 = lg[tl][1], l2 = lg[tl][2], l3 = lg[tl][3];
    float m = fmaxf(fmaxf(l0, l1), fmaxf(l2, l3));
    float e0 = __expf(l0 - m), e1 = __expf(l1 - m), e2 = __expf(l2 - m), e3 = __expf(l3 - m);
    float den = e0 + e1 + e2 + e3;
    float ek = (kx == 0) ? e0 : (kx == 1) ? e1 : (kx == 2) ? e2 : e3;
    cf[tl][kx] = ek / den;
  }
  __syncthreads();
  {
    const int tl = tid & 63, part = tid >> 6;
    float s = 0.f;
    for (int i = 0; i < 64; ++i) {
      const int cc = part * 64 + i;
      unsigned short us = c16[((size_t)(cc >> 3) * 512 + (t0 + tl)) * 8 + (cc & 7)];
      s += b2f(us) * Wr[cc];
    }
    rp[part][tl] = s;
  }
  __syncthreads();
  if (tid < 64)
    ratio[t0 + tid] = rp[0][tid] + rp[1][tid] + rp[2][tid] + rp[3][tid] + br[0];
  {
    const int tl = tid & 63, dp = tid >> 6;
    for (int s = 0; s < 32; ++s) {
      const int dg = dp * 32 + s;
      const float cv = cf[tl][dg >> 5];
      uint4 h1 = *(const uint4*)&H[(size_t)(t0 + tl) * 2304 + dg * 8];
      uint4 u1;
      u1.x = pk2(b2f((unsigned short)(h1.x & 0xFFFF)) * cv, b2f((unsigned short)(h1.x >> 16)) * cv);
      u1.y = pk2(b2f((unsigned short)(h1.y & 0xFFFF)) * cv, b2f((unsigned short)(h1.y >> 16)) * cv);
      u1.z = pk2(b2f((unsigned short)(h1.z & 0xFFFF)) * cv, b2f((unsigned short)(h1.z >> 16)) * cv);
      u1.w = pk2(b2f((unsigned short)(h1.w & 0xFFFF)) * cv, b2f((unsigned short)(h1.w >> 16)) * cv);
      G1u[(size_t)dg * 512 + t0 + tl] = u1;
      uint4 h2 = *(const uint4*)&H[(size_t)(t0 + tl) * 2304 + 1024 + dg * 8];
      uint4 u2;
      u2.x = pk2(b2f((unsigned short)(h2.x & 0xFFFF)) * cv, b2f((unsigned short)(h2.x >> 16)) * cv);
      u2.y = pk2(b2f((unsigned short)(h2.y & 0xFFFF)) * cv, b2f((unsigned short)(h2.y >> 16)) * cv);
      u2.z = pk2(b2f((unsigned short)(h2.z & 0xFFFF)) * cv, b2f((unsigned short)(h2.z >> 16)) * cv);
      u2.w = pk2(b2f((unsigned short)(h2.w & 0xFFFF)) * cv, b2f((unsigned short)(h2.w >> 16)) * cv);
      G2u[(size_t)dg * 512 + t0 + tl] = u2;
    }
  }
  if (tid < 64) {  // coeff run 128
    uint4 u;
    u.x = pk2(cf[tid][0], cf[tid][1]);
    u.y = pk2(cf[tid][2], cf[tid][3]);
    u.z = 0; u.w = 0;
    G1u[(size_t)128 * 512 + t0 + tid] = u;
    G2u[(size_t)128 * 512 + t0 + tid] = u;
  } else {  // zero runs 129..131
    const int idx = tid - 64;
    if (idx < 192) {
      uint4 z; z.x = 0; z.y = 0; z.z = 0; z.w = 0;
      G1u[(size_t)(129 + (idx >> 6)) * 512 + t0 + (idx & 63)] = z;
      G2u[(size_t)(129 + (idx >> 6)) * 512 + t0 + (idx & 63)] = z;
    }
  }
}

// ---------------------------------------------------------------------------
// K4/K5: M = G @ W (+coeff-mixed bias via tail K-step).
// M=512,K=1024(+32),N=32768. BM=BN=128, BK=64, 4 waves of 64x64.
// ---------------------------------------------------------------------------
__global__ __launch_bounds__(256) void k_biggemm(
    const uint4* __restrict__ Gu, const float* __restrict__ W,
    const float* __restrict__ bvec, unsigned short* __restrict__ Mout) {
  const int tid = threadIdx.x;
  const int m0 = blockIdx.x * 128, n0 = blockIdx.y * 128;
  __shared__ uint4 As[8 * 128];
  __shared__ uint4 Bs[8 * 128];
  const bf16x8* Af = reinterpret_cast<const bf16x8*>(As);
  const bf16x8* Bf = reinterpret_cast<const bf16x8*>(Bs);
  const int lane = tid & 63, w = tid >> 6;
  const int q = lane >> 4, rr = lane & 15;
  const int wm = (w >> 1) * 64, wn = (w & 1) * 64;
  const int colB = tid & 127, half = tid >> 7;

  fx4 acc[4][4];
#pragma unroll
  for (int i = 0; i < 4; ++i)
#pragma unroll
    for (int j = 0; j < 4; ++j) acc[i][j] = 0;

  for (int kt = 0; kt < 16; ++kt) {
#pragma unroll
    for (int s = 0; s < 4; ++s) {  // A: 16x 1KB global_load_lds chunks
      const int ch = w * 4 + s;
      const int run = ch >> 1, hf = ch & 1;
      gl2lds16(Gu + (size_t)(kt * 8 + run) * 512 + m0 + hf * 64 + lane,
               (void*)(As + run * 128 + hf * 64));
    }
    {  // B: scalar coalesced fp32 loads, per-thread column, contiguous LDS writes
#pragma unroll
      for (int grp = 0; grp < 2; ++grp) {
        float v[16];
        const float* wp = W + (size_t)(kt * 64 + half * 32 + grp * 16) * NN + n0 + colB;
#pragma unroll
        for (int kk = 0; kk < 16; ++kk) v[kk] = wp[(size_t)kk * NN];
        Bs[(half * 4 + grp * 2 + 0) * 128 + colB] = pk8(v);
        Bs[(half * 4 + grp * 2 + 1) * 128 + colB] = pk8(v + 8);
      }
    }
    __syncthreads();
#pragma unroll
    for (int ks = 0; ks < 2; ++ks) {
      bf16x8 a[4], b[4];
      const int ro = (ks * 4 + q) * 128;
#pragma unroll
      for (int f = 0; f < 4; ++f) a[f] = Af[ro + wm + f * 16 + rr];
#pragma unroll
      for (int f = 0; f < 4; ++f) b[f] = Bf[ro + wn + f * 16 + rr];
#pragma unroll
      for (int fi = 0; fi < 4; ++fi)
#pragma unroll
        for (int fj = 0; fj < 4; ++fj) acc[fi][fj] = MFMA(a[fi], b[fj], acc[fi][fj]);
    }
    __syncthreads();
  }
  // tail K-step: A runs 128..131 (coeffs + zeros), B rows = bvec(4) + zeros
#pragma unroll
  for (int s = 0; s < 2; ++s) {
    const int ch = w * 2 + s;
    const int run = ch >> 1, hf = ch & 1;
    gl2lds16(Gu + (size_t)(128 + run) * 512 + m0 + hf * 64 + lane,
             (void*)(As + run * 128 + hf * 64));
  }
  if (half == 0) {
#pragma unroll
    for (int r = 0; r < 4; ++r) {
      float v8[8];
#pragma unroll
      for (int j = 0; j < 8; ++j) {
        const int kk = r * 8 + j;
        v8[j] = (kk < 4) ? bvec[(size_t)kk * NN + n0 + colB] : 0.f;
      }
      Bs[r * 128 + colB] = pk8(v8);
    }
  }
  __syncthreads();
  {
    bf16x8 a[4], b[4];
    const int ro = q * 128;
#pragma unroll
    for (int f = 0; f < 4; ++f) a[f] = Af[ro + wm + f * 16 + rr];
#pragma unroll
    for (int f = 0; f < 4; ++f) b[f] = Bf[ro + wn + f * 16 + rr];
#pragma unroll
    for (int fi = 0; fi < 4; ++fi)
#pragma unroll
      for (int fj = 0; fj < 4; ++fj) acc[fi][fj] = MFMA(a[fi], b[fj], acc[fi][fj]);
  }
  // epilogue: bf16 store (D layout: col=lane&15, row=(lane>>4)*4+reg)
#pragma unroll
  for (int fi = 0; fi < 4; ++fi) {
    const int tb = m0 + wm + fi * 16 + q * 4;
#pragma unroll
    for (int fj = 0; fj < 4; ++fj) {
      const fx4 v = acc[fi][fj];
      const int cc = n0 + wn + fj * 16 + rr;
#pragma unroll
      for (int reg = 0; reg < 4; ++reg)
        Mout[(size_t)(tb + reg) * NN + cc] = f2bf(v[reg]);
    }
  }
}

// ---------------------------------------------------------------------------
// K6: x1o[t,g,o] = sum_i x[t,g*32+i] * M1[t,g*1024+i*32+o]; store transposed
// XT[t][o*32+g] so stage 2 reads x2[g][i] contiguously.
// ---------------------------------------------------------------------------
__global__ __launch_bounds__(256) void k_monarch1(
    const float* __restrict__ x, const unsigned short* __restrict__ M1,
    float* __restrict__ XT) {
  const int tt = blockIdx.x, tid = threadIdx.x;
  __shared__ float xs[1024];
  __shared__ float xo[1024];
  *(float4*)&xs[tid * 4] = *(const float4*)&x[(size_t)tt * 1024 + tid * 4];
  __syncthreads();
  const int g = tid >> 3, ob = (tid & 7) * 4;
  const unsigned short* mrow = M1 + (size_t)tt * NN + g * 1024 + ob;
  float a0 = 0, a1 = 0, a2 = 0, a3 = 0;
#pragma unroll
  for (int i = 0; i < 32; ++i) {
    ushort4 mv = *(const ushort4*)&mrow[i * 32];
    const float xv = xs[g * 32 + i];
    a0 += xv * b2f(mv.x); a1 += xv * b2f(mv.y);
    a2 += xv * b2f(mv.z); a3 += xv * b2f(mv.w);
  }
  xo[(ob + 0) * 32 + g] = a0; xo[(ob + 1) * 32 + g] = a1;
  xo[(ob + 2) * 32 + g] = a2; xo[(ob + 3) * 32 + g] = a3;
  __syncthreads();
  *(float4*)&XT[(size_t)tt * 1024 + tid * 4] = *(const float4*)&xo[tid * 4];
}

// ---------------------------------------------------------------------------
// K7: out[t, g*32+o] = (sum_i XT[t][g*32+i]*M2[t,g*1024+i*32+o])*ratio + biasout
// ---------------------------------------------------------------------------
__global__ __launch_bounds__(256) void k_monarch2(
    const unsigned short* __restrict__ M2, const float* __restrict__ XT,
    const float* __restrict__ biasout, const float* __restrict__ ratio,
    float* __restrict__ out) {
  const int tt = blockIdx.x, tid = threadIdx.x;
  __shared__ float xs[1024];
  *(float4*)&xs[tid * 4] = *(const float4*)&XT[(size_t)tt * 1024 + tid * 4];
  __syncthreads();
  const int g = tid >> 3, ob = (tid & 7) * 4;
  const unsigned short* mrow = M2 + (size_t)tt * NN + g * 1024 + ob;
  float a0 = 0, a1 = 0, a2 = 0, a3 = 0;
#pragma unroll
  for (int i = 0; i < 32; ++i) {
    ushort4 mv = *(const ushort4*)&mrow[i * 32];
    const float xv = xs[g * 32 + i];
    a0 += xv * b2f(mv.x); a1 += xv * b2f(mv.y);
    a2 += xv * b2f(mv.z); a3 += xv * b2f(mv.w);
  }
  const float r = ratio[tt];
  float4 bo = *(const float4*)&biasout[(size_t)tt * 1024 + tid * 4];
  float4 o;
  o.x = a0 * r + bo.x; o.y = a1 * r + bo.y;
  o.z = a2 * r + bo.z; o.w = a3 * r + bo.w;
  *(float4*)&out[(size_t)tt * 1024 + tid * 4] = o;
}

// ---------------------------------------------------------------------------
extern "C" void kernel_launch(void* const* d_in, const int* in_sizes, int n_in,
                              void* d_out, int out_size, void* d_ws, size_t ws_size,
                              hipStream_t stream) {
  (void)in_sizes; (void)n_in; (void)out_size; (void)ws_size;
  const float* x   = (const float*)d_in[0];
  const float* Wc  = (const float*)d_in[1];
  const float* bc  = (const float*)d_in[2];
  const float* W1a = (const float*)d_in[3];
  const float* b1a = (const float*)d_in[4];
  const float* W1b = (const float*)d_in[5];
  const float* b1b = (const float*)d_in[6];
  const float* W2a = (const float*)d_in[7];
  const float* b2a = (const float*)d_in[8];
  const float* W2b = (const float*)d_in[9];
  const float* b2b = (const float*)d_in[10];
  const float* Wm1 = (const float*)d_in[11];
  const float* bm1 = (const float*)d_in[12];
  const float* Wm2 = (const float*)d_in[13];
  const float* bm2 = (const float*)d_in[14];
  const float* Wb  = (const float*)d_in[15];
  const float* bb  = (const float*)d_in[16];
  const float* Wr  = (const float*)d_in[17];
  const float* br  = (const float*)d_in[18];
  float* out = (float*)d_out;

  char* ws = (char*)d_ws;
  uint4* c_u4            = (uint4*)(ws + 0);          // 36*512*16  = 294912
  unsigned short* c16    = (unsigned short*)c_u4;
  unsigned short* H      = (unsigned short*)(ws + 294912);   // 512*2304*2 = 2359296
  float* biasout         = (float*)(ws + 2654208);           // 512*1024*4 = 2097152
  uint4* G1u             = (uint4*)(ws + 4751360);           // 132*512*16 = 1081344
  uint4* G2u             = (uint4*)(ws + 5832704);           // 132*512*16 = 1081344
  float* ratio           = (float*)(ws + 6914048);           // 512*4 (+pad)
  float* XT              = (float*)(ws + 6918144);           // 512*1024*4 = 2097152
  unsigned short* M      = (unsigned short*)(ws + 9015296);  // 512*32768*2 = 33554432

  k1_compress<<<dim3(8, 4), 256, 0, stream>>>(x, Wc, bc, c_u4);
  k2_hyper<<<dim3(8, 52), 256, 0, stream>>>(c_u4, W1a, b1a, W2a, b2a, Wm1, bm1,
                                            Wb, bb, H, biasout);
  k3_prep<<<8, 256, 0, stream>>>(H, c16, Wm2, bm2, Wr, br, G1u, G2u, ratio);
  k_biggemm<<<dim3(4, 256), 256, 0, stream>>>(G1u, W1b, b1b, M);
  k_monarch1<<<512, 256, 0, stream>>>(x, M, XT);
  k_biggemm<<<dim3(4, 256), 256, 0, stream>>>(G2u, W2b, b2b, M);
  k_monarch2<<<512, 256, 0, stream>>>(M, XT, biasout, ratio, out);
}

// Round 2
// 472.861 us; speedup vs baseline: 1.0552x; 1.0552x over previous
//
#include <hip/hip_runtime.h>

// ---------------------------------------------------------------------------
// HyperMoMixLinear on MI355X.
//  K1 compress:  c = silu(x@Wc+bc)            [512,1024]@[1024,256]
//  K2 hyper:     H = silu(c@[W1a|W2a|Wm1]+b), biasout = c@Wb+bb   (N=3328)
//  K3 prep:      coeffs=softmax(mixh@Wm2+bm2), ratio=c@Wr+br, G=coeff*h (+tails)
//  K4 biggemm:   M1 = G1@W1b(+coeff-mixed b1b)  [512,1024]@[1024,32768]
//  K6 monarch1:  x1o = einsum(x, M1) -> XT (transposed layout)
//  K5 biggemm:   M2 = G2@W2b(+b2b)   (reuses M buffer)
//  K7 monarch2:  out = einsum(XT, M2)*ratio + biasout
// Activations (c, H, G) live in "unit" layout: 16B unit = 8 consecutive
// k-channels of one token; unit index = (k>>3)*512 + token -> GEMM A-staging
// is pure global_load_lds and k3's scaling pass is coalesced on both sides.
// biggemm: B loads are dwordx4 + register transpose, software-pipelined one
// K-tile ahead (loads issued after the 2nd barrier, consumed next iter so the
// MFMA span hides latency); grid is XCD-swizzled so the 4 m-tiles sharing an
// n-tile of W land on the same XCD's L2 (W fetched once).
// ---------------------------------------------------------------------------

typedef __bf16 bf16x8 __attribute__((ext_vector_type(8)));
typedef float  fx4    __attribute__((ext_vector_type(4)));

#define NN 32768

__device__ __forceinline__ unsigned short f2bf(float f) {
  union { float f; unsigned u; } v; v.f = f;
  unsigned r = v.u + 0x7FFFu + ((v.u >> 16) & 1u);
  return (unsigned short)(r >> 16);
}
__device__ __forceinline__ unsigned pk2(float lo, float hi) {
  return (unsigned)f2bf(lo) | ((unsigned)f2bf(hi) << 16);
}
__device__ __forceinline__ float b2f(unsigned short s) {
  union { unsigned u; float f; } v; v.u = ((unsigned)s) << 16; return v.f;
}
__device__ __forceinline__ void up8(uint4 h, float* f) {
  f[0] = b2f((unsigned short)(h.x & 0xFFFF)); f[1] = b2f((unsigned short)(h.x >> 16));
  f[2] = b2f((unsigned short)(h.y & 0xFFFF)); f[3] = b2f((unsigned short)(h.y >> 16));
  f[4] = b2f((unsigned short)(h.z & 0xFFFF)); f[5] = b2f((unsigned short)(h.z >> 16));
  f[6] = b2f((unsigned short)(h.w & 0xFFFF)); f[7] = b2f((unsigned short)(h.w >> 16));
}
__device__ __forceinline__ uint4 scale8(uint4 h, float cv) {
  uint4 u;
  u.x = pk2(b2f((unsigned short)(h.x & 0xFFFF)) * cv, b2f((unsigned short)(h.x >> 16)) * cv);
  u.y = pk2(b2f((unsigned short)(h.y & 0xFFFF)) * cv, b2f((unsigned short)(h.y >> 16)) * cv);
  u.z = pk2(b2f((unsigned short)(h.z & 0xFFFF)) * cv, b2f((unsigned short)(h.z >> 16)) * cv);
  u.w = pk2(b2f((unsigned short)(h.w & 0xFFFF)) * cv, b2f((unsigned short)(h.w >> 16)) * cv);
  return u;
}
__device__ __forceinline__ float silu_f(float x) { return x / (1.f + __expf(-x)); }

__device__ __forceinline__ void gl2lds16(const void* g, void* l) {
  __builtin_amdgcn_global_load_lds(
      (const __attribute__((address_space(1))) unsigned int*)g,
      (__attribute__((address_space(3))) unsigned int*)l, 16, 0, 0);
}

#define MFMA(a, b, c) __builtin_amdgcn_mfma_f32_16x16x32_bf16((a), (b), (c), 0, 0, 0)

// ---------------------------------------------------------------------------
// K1: c = silu(x @ Wc + bc).  M=512,K=1024,N=256.  BM=BN=64, BK=64.
// ---------------------------------------------------------------------------
__global__ __launch_bounds__(256) void k1_compress(
    const float* __restrict__ x, const float* __restrict__ Wc,
    const float* __restrict__ bc, uint4* __restrict__ c_u4) {
  const int tid = threadIdx.x;
  const int m0 = blockIdx.x * 64, n0 = blockIdx.y * 64;
  __shared__ uint4 As[8 * 64];
  __shared__ uint4 Bs[8 * 64];
  const bf16x8* Af = reinterpret_cast<const bf16x8*>(As);
  const bf16x8* Bf = reinterpret_cast<const bf16x8*>(Bs);
  uint2* Bs2 = reinterpret_cast<uint2*>(Bs);
  const int lane = tid & 63, w = tid >> 6;
  const int q = lane >> 4, rr = lane & 15;
  const int wm = (w >> 1) * 32, wn = (w & 1) * 32;
  // B-load mapping: 4 consecutive cols x 4 k's per thread (dwordx4 loads)
  const int bc4 = (tid & 15) * 4;
  const int brk = tid >> 4;            // 0..15
  const int br8 = brk & 7, bh = brk >> 3;
  fx4 a00 = 0, a01 = 0, a10 = 0, a11 = 0;

  for (int kt = 0; kt < 16; ++kt) {
    const int k0 = kt * 64;
    {  // A: x fp32 -> bf16 units [run][m]
      const int run = tid & 7, mb = tid >> 3;
#pragma unroll
      for (int s = 0; s < 2; ++s) {
        const int m = mb + 32 * s;
        const float* src = x + (size_t)(m0 + m) * 1024 + k0 + run * 8;
        fx4 f0 = *(const fx4*)src;
        fx4 f1 = *(const fx4*)(src + 4);
        uint4 u; u.x = pk2(f0[0], f0[1]); u.y = pk2(f0[2], f0[3]);
        u.z = pk2(f1[0], f1[1]); u.w = pk2(f1[2], f1[3]);
        As[run * 64 + m] = u;
      }
    }
    {  // B: Wc dwordx4 loads + register transpose
      const float* bp = Wc + (size_t)(k0 + br8 * 8 + bh * 4) * 256 + n0 + bc4;
      fx4 f0 = *(const fx4*)(bp);
      fx4 f1 = *(const fx4*)(bp + 256);
      fx4 f2 = *(const fx4*)(bp + 512);
      fx4 f3 = *(const fx4*)(bp + 768);
#pragma unroll
      for (int j = 0; j < 4; ++j) {
        uint2 u; u.x = pk2(f0[j], f1[j]); u.y = pk2(f2[j], f3[j]);
        Bs2[((br8 * 64 + bc4 + j) << 1) + bh] = u;
      }
    }
    __syncthreads();
#pragma unroll
    for (int ks = 0; ks < 2; ++ks) {
      const int ro = (ks * 4 + q) * 64;
      bf16x8 fa0 = Af[ro + wm + rr];
      bf16x8 fa1 = Af[ro + wm + 16 + rr];
      bf16x8 fb0 = Bf[ro + wn + rr];
      bf16x8 fb1 = Bf[ro + wn + 16 + rr];
      a00 = MFMA(fa0, fb0, a00); a01 = MFMA(fa0, fb1, a01);
      a10 = MFMA(fa1, fb0, a10); a11 = MFMA(fa1, fb1, a11);
    }
    __syncthreads();
  }
  {  // tail: A const-one channel, B row = bc
    const int r4 = tid >> 6, m = tid & 63;
    uint4 u; u.x = (r4 == 0) ? 0x3F80u : 0u; u.y = 0; u.z = 0; u.w = 0;
    As[r4 * 64 + m] = u;
    uint4 ub; ub.x = (r4 == 0) ? (unsigned)f2bf(bc[n0 + m]) : 0u;
    ub.y = 0; ub.z = 0; ub.w = 0;
    Bs[r4 * 64 + m] = ub;
  }
  __syncthreads();
  {
    const int ro = q * 64;
    bf16x8 fa0 = Af[ro + wm + rr];
    bf16x8 fa1 = Af[ro + wm + 16 + rr];
    bf16x8 fb0 = Bf[ro + wn + rr];
    bf16x8 fb1 = Bf[ro + wn + 16 + rr];
    a00 = MFMA(fa0, fb0, a00); a01 = MFMA(fa0, fb1, a01);
    a10 = MFMA(fa1, fb0, a10); a11 = MFMA(fa1, fb1, a11);
  }
  unsigned short* c16 = (unsigned short*)c_u4;
#pragma unroll
  for (int fi = 0; fi < 2; ++fi) {
#pragma unroll
    for (int fj = 0; fj < 2; ++fj) {
      fx4 v = (fi == 0) ? (fj == 0 ? a00 : a01) : (fj == 0 ? a10 : a11);
      const int cc = n0 + wn + fj * 16 + rr;
#pragma unroll
      for (int reg = 0; reg < 4; ++reg) {
        const int t = m0 + wm + fi * 16 + q * 4 + reg;
        c16[((size_t)(cc >> 3) * 512 + t) * 8 + (cc & 7)] = f2bf(silu_f(v[reg]));
      }
    }
  }
  if (blockIdx.y == 0) {  // const-one run 32 + zero runs 33..35
    const int r4 = tid >> 6, m = tid & 63;
    uint4 u; u.x = (r4 == 0) ? 0x3F80u : 0u; u.y = 0; u.z = 0; u.w = 0;
    c_u4[(size_t)(32 + r4) * 512 + m0 + m] = u;
  }
}

// ---------------------------------------------------------------------------
// K2: H = silu(c@{W1a,W2a,Wm1}+bias) -> unit layout, biasout = c@Wb+bb.
// M=512, K=256(+tail), N=3328. BM=BN=64.
// ---------------------------------------------------------------------------
__global__ __launch_bounds__(256) void k2_hyper(
    const uint4* __restrict__ c_u4,
    const float* __restrict__ W1a, const float* __restrict__ b1a,
    const float* __restrict__ W2a, const float* __restrict__ b2a,
    const float* __restrict__ Wm1, const float* __restrict__ bm1,
    const float* __restrict__ Wb, const float* __restrict__ bb,
    unsigned short* __restrict__ H, float* __restrict__ biasout) {
  const int tid = threadIdx.x;
  const int m0 = blockIdx.x * 64, n0 = blockIdx.y * 64;
  __shared__ uint4 As[8 * 64];
  __shared__ uint4 Bs[8 * 64];
  const bf16x8* Af = reinterpret_cast<const bf16x8*>(As);
  const bf16x8* Bf = reinterpret_cast<const bf16x8*>(Bs);
  uint2* Bs2 = reinterpret_cast<uint2*>(Bs);
  const int lane = tid & 63, w = tid >> 6;
  const int q = lane >> 4, rr = lane & 15;
  const int wm = (w >> 1) * 32, wn = (w & 1) * 32;
  const int bc4 = (tid & 15) * 4;
  const int brk = tid >> 4;
  const int br8 = brk & 7, bh = brk >> 3;

  const float* bbase; const float* biasv; int bstride;
  if (n0 < 1024) {
    const int kx = n0 >> 8;
    bbase = W1a + (size_t)kx * 65536 + (n0 & 255); bstride = 256;
    biasv = b1a + kx * 256 + (n0 & 255);
  } else if (n0 < 2048) {
    const int mm = n0 - 1024; const int kx = mm >> 8;
    bbase = W2a + (size_t)kx * 65536 + (mm & 255); bstride = 256;
    biasv = b2a + kx * 256 + (mm & 255);
  } else if (n0 < 2304) {
    bbase = Wm1 + (n0 - 2048); bstride = 256; biasv = bm1 + (n0 - 2048);
  } else {
    bbase = Wb + (n0 - 2304); bstride = 1024; biasv = bb + (n0 - 2304);
  }

  fx4 a00 = 0, a01 = 0, a10 = 0, a11 = 0;
  for (int kt = 0; kt < 4; ++kt) {
#pragma unroll
    for (int s = 0; s < 2; ++s) {
      const int run = w * 2 + s;
      gl2lds16(c_u4 + (size_t)(kt * 8 + run) * 512 + m0 + lane, (void*)(As + run * 64));
    }
    {
      const float* bp = bbase + (size_t)(kt * 64 + br8 * 8 + bh * 4) * bstride + bc4;
      fx4 f0 = *(const fx4*)(bp);
      fx4 f1 = *(const fx4*)(bp + bstride);
      fx4 f2 = *(const fx4*)(bp + 2 * bstride);
      fx4 f3 = *(const fx4*)(bp + 3 * bstride);
#pragma unroll
      for (int j = 0; j < 4; ++j) {
        uint2 u; u.x = pk2(f0[j], f1[j]); u.y = pk2(f2[j], f3[j]);
        Bs2[((br8 * 64 + bc4 + j) << 1) + bh] = u;
      }
    }
    __syncthreads();
#pragma unroll
    for (int ks = 0; ks < 2; ++ks) {
      const int ro = (ks * 4 + q) * 64;
      bf16x8 fa0 = Af[ro + wm + rr];
      bf16x8 fa1 = Af[ro + wm + 16 + rr];
      bf16x8 fb0 = Bf[ro + wn + rr];
      bf16x8 fb1 = Bf[ro + wn + 16 + rr];
      a00 = MFMA(fa0, fb0, a00); a01 = MFMA(fa0, fb1, a01);
      a10 = MFMA(fa1, fb0, a10); a11 = MFMA(fa1, fb1, a11);
    }
    __syncthreads();
  }
  {  // tail
    gl2lds16(c_u4 + (size_t)(32 + w) * 512 + m0 + lane, (void*)(As + w * 64));
    const int r4 = tid >> 6, col = tid & 63;
    uint4 ub; ub.x = (r4 == 0) ? (unsigned)f2bf(biasv[col]) : 0u;
    ub.y = 0; ub.z = 0; ub.w = 0;
    Bs[r4 * 64 + col] = ub;
  }
  __syncthreads();
  {
    const int ro = q * 64;
    bf16x8 fa0 = Af[ro + wm + rr];
    bf16x8 fa1 = Af[ro + wm + 16 + rr];
    bf16x8 fb0 = Bf[ro + wn + rr];
    bf16x8 fb1 = Bf[ro + wn + 16 + rr];
    a00 = MFMA(fa0, fb0, a00); a01 = MFMA(fa0, fb1, a01);
    a10 = MFMA(fa1, fb0, a10); a11 = MFMA(fa1, fb1, a11);
  }
#pragma unroll
  for (int fi = 0; fi < 2; ++fi) {
#pragma unroll
    for (int fj = 0; fj < 2; ++fj) {
      fx4 v = (fi == 0) ? (fj == 0 ? a00 : a01) : (fj == 0 ? a10 : a11);
      const int cc = n0 + wn + fj * 16 + rr;
#pragma unroll
      for (int reg = 0; reg < 4; ++reg) {
        const int t = m0 + wm + fi * 16 + q * 4 + reg;
        if (n0 < 2304)
          H[(((size_t)(cc >> 3) * 512 + t) << 3) + (cc & 7)] = f2bf(silu_f(v[reg]));
        else
          biasout[(size_t)t * 1024 + (cc - 2304)] = v[reg];
      }
    }
  }
}

// ---------------------------------------------------------------------------
// K3: coeffs = softmax(mixh@Wm2+bm2); ratio = c@Wr+br; G = coeff*h (+tails).
// 64 blocks: blockIdx = tg (8 token groups) x dgrp (8 dg groups of 16).
// H in unit layout -> fully coalesced scaling pass.
// ---------------------------------------------------------------------------
__global__ __launch_bounds__(256) void k3_prep(
    const uint4* __restrict__ Hu, const uint4* __restrict__ c_u4,
    const float* __restrict__ Wm2, const float* __restrict__ bm2,
    const float* __restrict__ Wr, const float* __restrict__ br,
    uint4* __restrict__ G1u, uint4* __restrict__ G2u, float* __restrict__ ratio) {
  const int tid = threadIdx.x;
  const int tg = blockIdx.x & 7, dgrp = blockIdx.x >> 3;
  const int t0 = tg * 64;
  __shared__ float sWm2[1024];
  __shared__ float sWr[256];
  __shared__ float part[64][4][4];
  __shared__ float rp[64][4];
  __shared__ float cf[64][4];
  ((fx4*)sWm2)[tid] = ((const fx4*)Wm2)[tid];
  if (tid < 64) ((fx4*)sWr)[tid] = ((const fx4*)Wr)[tid];
  __syncthreads();
  const int tl = tid >> 2, kx = tid & 3;
  {
    float pe0 = 0, pe1 = 0, pe2 = 0, pe3 = 0, pr = 0;
#pragma unroll
    for (int i = 0; i < 8; ++i) {
      uint4 h  = Hu[(size_t)(256 + kx * 8 + i) * 512 + t0 + tl];
      uint4 cu = c_u4[(size_t)(kx * 8 + i) * 512 + t0 + tl];
      float hf[8], cv[8];
      up8(h, hf); up8(cu, cv);
#pragma unroll
      for (int j = 0; j < 8; ++j) {
        const int ch = kx * 64 + i * 8 + j;
        pe0 += hf[j] * sWm2[ch * 4 + 0];
        pe1 += hf[j] * sWm2[ch * 4 + 1];
        pe2 += hf[j] * sWm2[ch * 4 + 2];
        pe3 += hf[j] * sWm2[ch * 4 + 3];
        pr  += cv[j] * sWr[ch];
      }
    }
    part[tl][kx][0] = pe0; part[tl][kx][1] = pe1;
    part[tl][kx][2] = pe2; part[tl][kx][3] = pe3;
    rp[tl][kx] = pr;
  }
  __syncthreads();
  if (tid < 64) {
    float l[4];
#pragma unroll
    for (int e = 0; e < 4; ++e)
      l[e] = part[tid][0][e] + part[tid][1][e] + part[tid][2][e] + part[tid][3][e] + bm2[e];
    float m = fmaxf(fmaxf(l[0], l[1]), fmaxf(l[2], l[3]));
    float e0 = __expf(l[0] - m), e1 = __expf(l[1] - m);
    float e2 = __expf(l[2] - m), e3 = __expf(l[3] - m);
    float den = e0 + e1 + e2 + e3;
    cf[tid][0] = e0 / den; cf[tid][1] = e1 / den;
    cf[tid][2] = e2 / den; cf[tid][3] = e3 / den;
    if (dgrp == 0)
      ratio[t0 + tid] = rp[tid][0] + rp[tid][1] + rp[tid][2] + rp[tid][3] + br[0];
  }
  __syncthreads();
  const int tl2 = tid & 63, sub = tid >> 6;
#pragma unroll
  for (int i = 0; i < 4; ++i) {
    const int dg = dgrp * 16 + sub * 4 + i;
    const float cv = cf[tl2][dg >> 5];
    uint4 h1 = Hu[(size_t)dg * 512 + t0 + tl2];
    G1u[(size_t)dg * 512 + t0 + tl2] = scale8(h1, cv);
    uint4 h2 = Hu[(size_t)(128 + dg) * 512 + t0 + tl2];
    G2u[(size_t)dg * 512 + t0 + tl2] = scale8(h2, cv);
  }
  if (dgrp == 0) {
    if (tid < 64) {  // coeff run 128
      uint4 u;
      u.x = pk2(cf[tid][0], cf[tid][1]);
      u.y = pk2(cf[tid][2], cf[tid][3]);
      u.z = 0; u.w = 0;
      G1u[(size_t)128 * 512 + t0 + tid] = u;
      G2u[(size_t)128 * 512 + t0 + tid] = u;
    } else {  // zero runs 129..131
      const int idx = tid - 64;
      uint4 z; z.x = 0; z.y = 0; z.z = 0; z.w = 0;
      G1u[(size_t)(129 + (idx >> 6)) * 512 + t0 + (idx & 63)] = z;
      G2u[(size_t)(129 + (idx >> 6)) * 512 + t0 + (idx & 63)] = z;
    }
  }
}

// ---------------------------------------------------------------------------
// K4/K5: M = G @ W (+coeff-mixed bias via tail K-step).
// M=512,K=1024(+32),N=32768. BM=BN=128, BK=64, 4 waves of 64x64.
// XCD-swizzled grid; B dwordx4 loads pipelined one kt ahead.
// ---------------------------------------------------------------------------
__global__ __launch_bounds__(256) void k_biggemm(
    const uint4* __restrict__ Gu, const float* __restrict__ W,
    const float* __restrict__ bvec, unsigned short* __restrict__ Mout) {
  const int tid = threadIdx.x;
  const int p = blockIdx.x;
  const int xcd = p & 7, slot = p >> 3;
  const int m0 = (slot & 3) * 128;
  const int n0 = ((slot >> 2) * 8 + xcd) * 128;
  __shared__ uint4 As[8 * 128];
  __shared__ uint4 Bs[8 * 128];
  const bf16x8* Af = reinterpret_cast<const bf16x8*>(As);
  const bf16x8* Bf = reinterpret_cast<const bf16x8*>(Bs);
  const int lane = tid & 63, w = tid >> 6;
  const int q = lane >> 4, rr = lane & 15;
  const int wm = (w >> 1) * 64, wn = (w & 1) * 64;
  const int colB = tid & 127, half = tid >> 7;  // tail only
  // B-load mapping: 4 consecutive cols x full k-octet per thread
  const int bc4 = (tid & 31) * 4;
  const int br = tid >> 5;  // 0..7
  const float* wptr = W + n0 + bc4;

  fx4 acc[4][4];
#pragma unroll
  for (int i = 0; i < 4; ++i)
#pragma unroll
    for (int j = 0; j < 4; ++j) acc[i][j] = 0;

  fx4 breg[8];
#pragma unroll
  for (int kk = 0; kk < 8; ++kk)
    breg[kk] = *(const fx4*)(wptr + (size_t)(br * 8 + kk) * NN);

  for (int kt = 0; kt < 16; ++kt) {
    __syncthreads();
    // write B(kt) from regs -> LDS (register transpose k-major -> unit)
#pragma unroll
    for (int j = 0; j < 4; ++j) {
      uint4 u;
      u.x = pk2(breg[0][j], breg[1][j]);
      u.y = pk2(breg[2][j], breg[3][j]);
      u.z = pk2(breg[4][j], breg[5][j]);
      u.w = pk2(breg[6][j], breg[7][j]);
      Bs[br * 128 + bc4 + j] = u;
    }
    // stage A via global_load_lds (16B)
#pragma unroll
    for (int s = 0; s < 4; ++s) {
      const int ch = w * 4 + s;
      const int run = ch >> 1, hf = ch & 1;
      gl2lds16(Gu + (size_t)(kt * 8 + run) * 512 + m0 + hf * 64 + lane,
               (void*)(As + run * 128 + hf * 64));
    }
    __syncthreads();
    if (kt < 15) {  // prefetch B(kt+1); latency hidden behind MFMA below
#pragma unroll
      for (int kk = 0; kk < 8; ++kk)
        breg[kk] = *(const fx4*)(wptr + (size_t)((kt + 1) * 64 + br * 8 + kk) * NN);
    }
#pragma unroll
    for (int ks = 0; ks < 2; ++ks) {
      bf16x8 a[4], b[4];
      const int ro = (ks * 4 + q) * 128;
#pragma unroll
      for (int f = 0; f < 4; ++f) a[f] = Af[ro + wm + f * 16 + rr];
#pragma unroll
      for (int f = 0; f < 4; ++f) b[f] = Bf[ro + wn + f * 16 + rr];
#pragma unroll
      for (int fi = 0; fi < 4; ++fi)
#pragma unroll
        for (int fj = 0; fj < 4; ++fj) acc[fi][fj] = MFMA(a[fi], b[fj], acc[fi][fj]);
    }
  }
  __syncthreads();
  // tail K-step: A runs 128..131 (coeffs + zeros), B rows = bvec(4) + zeros
#pragma unroll
  for (int s = 0; s < 2; ++s) {
    const int ch = w * 2 + s;
    const int run = ch >> 1, hf = ch & 1;
    gl2lds16(Gu + (size_t)(128 + run) * 512 + m0 + hf * 64 + lane,
             (void*)(As + run * 128 + hf * 64));
  }
  if (half == 0) {
#pragma unroll
    for (int r = 0; r < 4; ++r) {
      float v8[8];
#pragma unroll
      for (int j = 0; j < 8; ++j) {
        const int kk = r * 8 + j;
        v8[j] = (kk < 4) ? bvec[(size_t)kk * NN + n0 + colB] : 0.f;
      }
      uint4 u; u.x = pk2(v8[0], v8[1]); u.y = pk2(v8[2], v8[3]);
      u.z = pk2(v8[4], v8[5]); u.w = pk2(v8[6], v8[7]);
      Bs[r * 128 + colB] = u;
    }
  }
  __syncthreads();
  {
    bf16x8 a[4], b[4];
    const int ro = q * 128;
#pragma unroll
    for (int f = 0; f < 4; ++f) a[f] = Af[ro + wm + f * 16 + rr];
#pragma unroll
    for (int f = 0; f < 4; ++f) b[f] = Bf[ro + wn + f * 16 + rr];
#pragma unroll
    for (int fi = 0; fi < 4; ++fi)
#pragma unroll
      for (int fj = 0; fj < 4; ++fj) acc[fi][fj] = MFMA(a[fi], b[fj], acc[fi][fj]);
  }
#pragma unroll
  for (int fi = 0; fi < 4; ++fi) {
    const int tb = m0 + wm + fi * 16 + q * 4;
#pragma unroll
    for (int fj = 0; fj < 4; ++fj) {
      const fx4 v = acc[fi][fj];
      const int cc = n0 + wn + fj * 16 + rr;
#pragma unroll
      for (int reg = 0; reg < 4; ++reg)
        Mout[(size_t)(tb + reg) * NN + cc] = f2bf(v[reg]);
    }
  }
}

// ---------------------------------------------------------------------------
// K6: x1o[t,g,o] = sum_i x[t,g*32+i] * M1[t,g*1024+i*32+o]; store transposed.
// ---------------------------------------------------------------------------
__global__ __launch_bounds__(256) void k_monarch1(
    const float* __restrict__ x, const unsigned short* __restrict__ M1,
    float* __restrict__ XT) {
  const int tt = blockIdx.x, tid = threadIdx.x;
  __shared__ float xs[1024];
  __shared__ float xo[1024];
  *(float4*)&xs[tid * 4] = *(const float4*)&x[(size_t)tt * 1024 + tid * 4];
  __syncthreads();
  const int g = tid >> 3, ob = (tid & 7) * 4;
  const unsigned short* mrow = M1 + (size_t)tt * NN + g * 1024 + ob;
  float a0 = 0, a1 = 0, a2 = 0, a3 = 0;
#pragma unroll
  for (int i = 0; i < 32; ++i) {
    ushort4 mv = *(const ushort4*)&mrow[i * 32];
    const float xv = xs[g * 32 + i];
    a0 += xv * b2f(mv.x); a1 += xv * b2f(mv.y);
    a2 += xv * b2f(mv.z); a3 += xv * b2f(mv.w);
  }
  xo[(ob + 0) * 32 + g] = a0; xo[(ob + 1) * 32 + g] = a1;
  xo[(ob + 2) * 32 + g] = a2; xo[(ob + 3) * 32 + g] = a3;
  __syncthreads();
  *(float4*)&XT[(size_t)tt * 1024 + tid * 4] = *(const float4*)&xo[tid * 4];
}

// ---------------------------------------------------------------------------
// K7: out = (einsum(XT, M2)) * ratio + biasout
// ---------------------------------------------------------------------------
__global__ __launch_bounds__(256) void k_monarch2(
    const unsigned short* __restrict__ M2, const float* __restrict__ XT,
    const float* __restrict__ biasout, const float* __restrict__ ratio,
    float* __restrict__ out) {
  const int tt = blockIdx.x, tid = threadIdx.x;
  __shared__ float xs[1024];
  *(float4*)&xs[tid * 4] = *(const float4*)&XT[(size_t)tt * 1024 + tid * 4];
  __syncthreads();
  const int g = tid >> 3, ob = (tid & 7) * 4;
  const unsigned short* mrow = M2 + (size_t)tt * NN + g * 1024 + ob;
  float a0 = 0, a1 = 0, a2 = 0, a3 = 0;
#pragma unroll
  for (int i = 0; i < 32; ++i) {
    ushort4 mv = *(const ushort4*)&mrow[i * 32];
    const float xv = xs[g * 32 + i];
    a0 += xv * b2f(mv.x); a1 += xv * b2f(mv.y);
    a2 += xv * b2f(mv.z); a3 += xv * b2f(mv.w);
  }
  const float r = ratio[tt];
  float4 bo = *(const float4*)&biasout[(size_t)tt * 1024 + tid * 4];
  float4 o;
  o.x = a0 * r + bo.x; o.y = a1 * r + bo.y;
  o.z = a2 * r + bo.z; o.w = a3 * r + bo.w;
  *(float4*)&out[(size_t)tt * 1024 + tid * 4] = o;
}

// ---------------------------------------------------------------------------
extern "C" void kernel_launch(void* const* d_in, const int* in_sizes, int n_in,
                              void* d_out, int out_size, void* d_ws, size_t ws_size,
                              hipStream_t stream) {
  (void)in_sizes; (void)n_in; (void)out_size; (void)ws_size;
  const float* x   = (const float*)d_in[0];
  const float* Wc  = (const float*)d_in[1];
  const float* bc  = (const float*)d_in[2];
  const float* W1a = (const float*)d_in[3];
  const float* b1a = (const float*)d_in[4];
  const float* W1b = (const float*)d_in[5];
  const float* b1b = (const float*)d_in[6];
  const float* W2a = (const float*)d_in[7];
  const float* b2a = (const float*)d_in[8];
  const float* W2b = (const float*)d_in[9];
  const float* b2b = (const float*)d_in[10];
  const float* Wm1 = (const float*)d_in[11];
  const float* bm1 = (const float*)d_in[12];
  const float* Wm2 = (const float*)d_in[13];
  const float* bm2 = (const float*)d_in[14];
  const float* Wb  = (const float*)d_in[15];
  const float* bb  = (const float*)d_in[16];
  const float* Wr  = (const float*)d_in[17];
  const float* br  = (const float*)d_in[18];
  float* out = (float*)d_out;

  char* ws = (char*)d_ws;
  uint4* c_u4            = (uint4*)(ws + 0);                 // 36*512*16  = 294912
  unsigned short* H      = (unsigned short*)(ws + 294912);   // 288*512*16 = 2359296
  float* biasout         = (float*)(ws + 2654208);           // 512*1024*4 = 2097152
  uint4* G1u             = (uint4*)(ws + 4751360);           // 132*512*16 = 1081344
  uint4* G2u             = (uint4*)(ws + 5832704);           // 132*512*16 = 1081344
  float* ratio           = (float*)(ws + 6914048);           // 512*4 (+pad)
  float* XT              = (float*)(ws + 6918144);           // 512*1024*4 = 2097152
  unsigned short* M      = (unsigned short*)(ws + 9015296);  // 512*32768*2 = 33554432

  k1_compress<<<dim3(8, 4), 256, 0, stream>>>(x, Wc, bc, c_u4);
  k2_hyper<<<dim3(8, 52), 256, 0, stream>>>(c_u4, W1a, b1a, W2a, b2a, Wm1, bm1,
                                            Wb, bb, H, biasout);
  k3_prep<<<64, 256, 0, stream>>>((const uint4*)H, c_u4, Wm2, bm2, Wr, br,
                                  G1u, G2u, ratio);
  k_biggemm<<<1024, 256, 0, stream>>>(G1u, W1b, b1b, M);
  k_monarch1<<<512, 256, 0, stream>>>(x, M, XT);
  k_biggemm<<<1024, 256, 0, stream>>>(G2u, W2b, b2b, M);
  k_monarch2<<<512, 256, 0, stream>>>(M, XT, biasout, ratio, out);
}